// Round 10
// baseline (84.674 us; speedup 1.0000x reference)
//
#include <hip/hip_runtime.h>
#include <hip/hip_bf16.h>

using u64 = unsigned long long;

constexpr int Bb    = 4;
constexpr int Nn    = 2048;
constexpr int INDIM = 64;
constexpr int HID   = 128;      // HIDDEN == OUT_DIM == 128
constexpr int NW    = Nn / 64;  // mask words per row = 32

// ---------------------------------------------------------------- normalize
__global__ __launch_bounds__(128) void k_norm(const float* __restrict__ emb,
                                              float* __restrict__ ne) {
    const int r = blockIdx.x, c = threadIdx.x;
    const float v = emb[(size_t)r * HID + c];
    __shared__ float red[128];
    red[c] = v * v;
    __syncthreads();
    for (int s = 64; s > 0; s >>= 1) {
        if (c < s) red[c] += red[c + s];
        __syncthreads();
    }
    const float tot = red[0];
    ne[(size_t)r * HID + c] = v * rsqrtf(tot + 1e-12f);
}

// -------------------- adj Gram: tiled 128x128 register GEMM + bit packing
// grid 16x16 = 256 blocks, 256 threads, 8x8 acc/thread, BK=32 staged in LDS.
// launch_bounds(256,2): cap VGPR at 128 -> 2 blocks/CU for latency hiding.
__global__ __launch_bounds__(256, 2) void k_adj(const float* __restrict__ ne,
                                                u64* __restrict__ maskw) {
    __shared__ float As[32][132];            // k-major, padded pitch
    __shared__ float Bs[32][132];
    __shared__ unsigned char mb[128][16];    // packed mask bytes
    const int i0 = (blockIdx.x >> 4) * 128;
    const int j0 = (blockIdx.x & 15) * 128;
    const int t  = threadIdx.x;
    const int tx = t & 15, ty = t >> 4;
    const int sr = t >> 1, sh = (t & 1) * 16;   // staging: row, k-half

    float acc[8][8];
    #pragma unroll
    for (int a = 0; a < 8; ++a)
        #pragma unroll
        for (int b = 0; b < 8; ++b) acc[a][b] = 0.f;

    for (int kc = 0; kc < HID; kc += 32) {
        const float* gA = ne + (size_t)(i0 + sr) * HID + kc + sh;
        const float* gB = ne + (size_t)(j0 + sr) * HID + kc + sh;
        #pragma unroll
        for (int e = 0; e < 16; e += 4) {
            const float4 va = *reinterpret_cast<const float4*>(gA + e);
            const float4 vb = *reinterpret_cast<const float4*>(gB + e);
            As[sh + e + 0][sr] = va.x; As[sh + e + 1][sr] = va.y;
            As[sh + e + 2][sr] = va.z; As[sh + e + 3][sr] = va.w;
            Bs[sh + e + 0][sr] = vb.x; Bs[sh + e + 1][sr] = vb.y;
            Bs[sh + e + 2][sr] = vb.z; Bs[sh + e + 3][sr] = vb.w;
        }
        __syncthreads();
        #pragma unroll 4
        for (int k = 0; k < 32; ++k) {
            float a[8], b[8];
            *reinterpret_cast<float4*>(&a[0]) = *reinterpret_cast<const float4*>(&As[k][ty * 8]);
            *reinterpret_cast<float4*>(&a[4]) = *reinterpret_cast<const float4*>(&As[k][ty * 8 + 4]);
            *reinterpret_cast<float4*>(&b[0]) = *reinterpret_cast<const float4*>(&Bs[k][tx * 8]);
            *reinterpret_cast<float4*>(&b[4]) = *reinterpret_cast<const float4*>(&Bs[k][tx * 8 + 4]);
            #pragma unroll
            for (int ii = 0; ii < 8; ++ii)
                #pragma unroll
                for (int jj = 0; jj < 8; ++jj)
                    acc[ii][jj] += a[ii] * b[jj];
        }
        __syncthreads();
    }

    #pragma unroll
    for (int e = 0; e < 8; ++e) {
        unsigned byte = 0;
        #pragma unroll
        for (int jj = 0; jj < 8; ++jj)
            if (acc[e][jj] > 0.5f) byte |= (1u << jj);
        mb[ty * 8 + e][tx] = (unsigned char)byte;
    }
    __syncthreads();
    {
        const int row = t >> 1, w = t & 1;
        const u64 bits = *reinterpret_cast<const u64*>(&mb[row][w * 8]);
        maskw[(size_t)(i0 + row) * NW + (j0 >> 6) + w] = bits;
    }
}

// --------- fused: h = x@Wp+bp (LDS) ; hh1 = h@W1 ; s1 reductions. 8 rows/block.
__global__ __launch_bounds__(128) void k_projhid(const float* __restrict__ x,
                                                 const float* __restrict__ Wp,
                                                 const float* __restrict__ bp,
                                                 const float* __restrict__ W1,
                                                 const float* __restrict__ a1s,
                                                 const float* __restrict__ a1d,
                                                 float* __restrict__ hh,
                                                 float* __restrict__ ssrc,
                                                 float* __restrict__ sdst) {
    const int r0 = blockIdx.x * 8;   // flattened b*N row base
    const int c  = threadIdx.x;
    __shared__ float hl[8][128];

    float acc[8];
    const float bias = bp[c];
    #pragma unroll
    for (int r = 0; r < 8; ++r) acc[r] = bias;
    #pragma unroll 4
    for (int k = 0; k < INDIM; ++k) {
        const float wp = Wp[k * HID + c];
        #pragma unroll
        for (int r = 0; r < 8; ++r)
            acc[r] += x[(size_t)(r0 + r) * INDIM + k] * wp;   // block-uniform -> s_load
    }
    #pragma unroll
    for (int r = 0; r < 8; ++r) hl[r][c] = acc[r];
    __syncthreads();

    float a2[8];
    #pragma unroll
    for (int r = 0; r < 8; ++r) a2[r] = 0.f;
    #pragma unroll 4
    for (int k = 0; k < HID; ++k) {
        const float w = W1[k * HID + c];
        #pragma unroll
        for (int r = 0; r < 8; ++r)
            a2[r] += hl[r][k] * w;                            // LDS broadcast
    }
    const float as = a1s[c], ad = a1d[c];
    #pragma unroll
    for (int r = 0; r < 8; ++r) {
        hh[(size_t)(r0 + r) * HID + c] = a2[r];
        float vs = a2[r] * as;
        float vd = a2[r] * ad;
        #pragma unroll
        for (int m = 1; m < 32; m <<= 1) {
            vs += __shfl_xor(vs, m, 32);
            vd += __shfl_xor(vd, m, 32);
        }
        if ((c & 31) == 0) {
            ssrc[(size_t)(r0 + r) * 4 + (c >> 5)] = vs;
            sdst[(size_t)(r0 + r) * 4 + (c >> 5)] = vd;
        }
    }
}

// --------- fused: gat layer1 (+GELU, LDS) ; hh2 = g@W2 ; s2 reductions. 8 rows/block.
__global__ __launch_bounds__(128) void k_gathid(const float* __restrict__ hh1,
                                                const float* __restrict__ s1s,
                                                const float* __restrict__ s1d,
                                                const u64* __restrict__ maskw,
                                                const float* __restrict__ b1v,
                                                const float* __restrict__ W2,
                                                const float* __restrict__ a2s,
                                                const float* __restrict__ a2d,
                                                float* __restrict__ hh2,
                                                float* __restrict__ s2s,
                                                float* __restrict__ s2d) {
    const int r0 = blockIdx.x * 8;
    const int bb = r0 >> 11;            // batch index
    const int c  = threadIdx.x;         // channel 0..127
    const int hd = c >> 5;              // head
    __shared__ float gl[8][128];

    for (int r = 0; r < 8; ++r) {
        const int row = r0 + r, i = row & (Nn - 1);
        const float sd = s1d[(size_t)row * 4 + hd];
        const u64* mrow = maskw + (size_t)i * NW;
        float m = -INFINITY, l = 0.f, a = 0.f;
        for (int w = 0; w < NW; ++w) {
            u64 word = mrow[w];
            while (word) {
                const int bit = __builtin_ctzll(word);
                word &= word - 1;
                const int jr = (bb << 11) + (w << 6) + bit;
                float e = sd + s1s[(size_t)jr * 4 + hd];
                e = e > 0.f ? e : 0.2f * e;
                const float v = hh1[(size_t)jr * HID + c];
                const float nm = fmaxf(m, e);
                const float sc = __expf(m - nm);
                const float p  = __expf(e - nm);
                l = l * sc + p; a = a * sc + p * v; m = nm;
            }
        }
        float o = (l > 0.f ? a / l : 0.f) + b1v[c];
        o = 0.5f * o * (1.f + erff(o * 0.70710678118654752f));
        gl[r][c] = o;
    }
    __syncthreads();

    float acc[8];
    #pragma unroll
    for (int r = 0; r < 8; ++r) acc[r] = 0.f;
    #pragma unroll 4
    for (int k = 0; k < HID; ++k) {
        const float w = W2[k * HID + c];
        #pragma unroll
        for (int r = 0; r < 8; ++r)
            acc[r] += gl[r][k] * w;                           // LDS broadcast
    }
    const float as = a2s[c], ad = a2d[c];
    #pragma unroll
    for (int r = 0; r < 8; ++r) {
        hh2[(size_t)(r0 + r) * HID + c] = acc[r];
        float vs = acc[r] * as;
        float vd = acc[r] * ad;
        #pragma unroll
        for (int m = 1; m < 32; m <<= 1) {
            vs += __shfl_xor(vs, m, 32);
            vd += __shfl_xor(vd, m, 32);
        }
        if ((c & 31) == 0) {
            s2s[(size_t)(r0 + r) * 4 + (c >> 5)] = vs;
            s2d[(size_t)(r0 + r) * 4 + (c >> 5)] = vd;
        }
    }
}

// ------------- final masked online-softmax aggregation (writes f32 d_out)
__global__ __launch_bounds__(64) void k_gat(const float* __restrict__ hh,
                                            const float* __restrict__ ssrc,
                                            const float* __restrict__ sdst,
                                            const u64* __restrict__ maskw,
                                            const float* __restrict__ bias,
                                            float* __restrict__ out) {
    const int row  = blockIdx.x;        // b*N + i
    const int i    = row & (Nn - 1);
    const int b    = row >> 11;
    const int lane = threadIdx.x;       // channels: lane (heads 0/1), lane+64 (heads 2/3)
    const int h0   = lane >> 5;
    const int h1   = 2 + h0;
    const float sd0 = sdst[(size_t)row * 4 + h0];
    const float sd1 = sdst[(size_t)row * 4 + h1];
    const u64* mrow = maskw + (size_t)i * NW;

    float m0 = -INFINITY, l0 = 0.f, a0 = 0.f;
    float m1 = -INFINITY, l1 = 0.f, a1 = 0.f;

    for (int w = 0; w < NW; ++w) {
        u64 word = mrow[w];
        while (word) {
            const int bit = __builtin_ctzll(word);
            word &= word - 1;
            const int jr = (b << 11) + (w << 6) + bit;
            float e0 = sd0 + ssrc[(size_t)jr * 4 + h0];
            e0 = e0 > 0.f ? e0 : 0.2f * e0;
            float e1 = sd1 + ssrc[(size_t)jr * 4 + h1];
            e1 = e1 > 0.f ? e1 : 0.2f * e1;
            const float v0 = hh[(size_t)jr * HID + lane];
            const float v1 = hh[(size_t)jr * HID + 64 + lane];
            float nm = fmaxf(m0, e0);
            float sc = __expf(m0 - nm);
            float p  = __expf(e0 - nm);
            l0 = l0 * sc + p; a0 = a0 * sc + p * v0; m0 = nm;
            nm = fmaxf(m1, e1);
            sc = __expf(m1 - nm);
            p  = __expf(e1 - nm);
            l1 = l1 * sc + p; a1 = a1 * sc + p * v1; m1 = nm;
        }
    }

    out[(size_t)row * HID + lane]      = (l0 > 0.f ? a0 / l0 : 0.f) + bias[lane];
    out[(size_t)row * HID + 64 + lane] = (l1 > 0.f ? a1 / l1 : 0.f) + bias[64 + lane];
}

// ---------------------------------------------------------------- launcher
extern "C" void kernel_launch(void* const* d_in, const int* in_sizes, int n_in,
                              void* d_out, int out_size, void* d_ws, size_t ws_size,
                              hipStream_t stream) {
    // dict order: x, embedding, Wp, bp, W1, a1_src, a1_dst, b1, W2, a2_src, a2_dst, b2
    const float* x   = (const float*)d_in[0];
    const float* emb = (const float*)d_in[1];
    const float* Wp  = (const float*)d_in[2];
    const float* bp  = (const float*)d_in[3];
    const float* W1  = (const float*)d_in[4];
    const float* a1s = (const float*)d_in[5];
    const float* a1d = (const float*)d_in[6];
    const float* b1  = (const float*)d_in[7];
    const float* W2  = (const float*)d_in[8];
    const float* a2s = (const float*)d_in[9];
    const float* a2d = (const float*)d_in[10];
    const float* b2  = (const float*)d_in[11];

    // Workspace: ~10 MB
    char* ws = (char*)d_ws;
    float* ne   = (float*)ws; ws += (size_t)Nn * HID * 4;          // 1 MB
    u64*  maskw = (u64*)ws;   ws += (size_t)Nn * NW * 8;           // 512 KB
    float* hh1  = (float*)ws; ws += (size_t)Bb * Nn * HID * 4;     // 4 MB
    float* hh2  = (float*)ws; ws += (size_t)Bb * Nn * HID * 4;     // 4 MB
    float* s1s  = (float*)ws; ws += (size_t)Bb * Nn * 4 * 4;       // 128 KB
    float* s1d  = (float*)ws; ws += (size_t)Bb * Nn * 4 * 4;       // 128 KB
    float* s2s  = (float*)ws; ws += (size_t)Bb * Nn * 4 * 4;       // 128 KB
    float* s2d  = (float*)ws; ws += (size_t)Bb * Nn * 4 * 4;       // 128 KB

    k_norm<<<Nn, 128, 0, stream>>>(emb, ne);
    k_adj<<<256, 256, 0, stream>>>(ne, maskw);
    k_projhid<<<Bb * Nn / 8, 128, 0, stream>>>(x, Wp, bp, W1, a1s, a1d, hh1, s1s, s1d);
    k_gathid<<<Bb * Nn / 8, 128, 0, stream>>>(hh1, s1s, s1d, maskw, b1, W2, a2s, a2d,
                                              hh2, s2s, s2d);
    k_gat<<<Bb * Nn, 64, 0, stream>>>(hh2, s2s, s2d, maskw, b2, (float*)d_out);
}

// Round 11
// 65.528 us; speedup vs baseline: 1.2922x; 1.2922x over previous
//
#include <hip/hip_runtime.h>
#include <hip/hip_bf16.h>

using u64 = unsigned long long;

constexpr int Bb    = 4;
constexpr int Nn    = 2048;
constexpr int INDIM = 64;
constexpr int HID   = 128;      // HIDDEN == OUT_DIM == 128
constexpr int NW    = Nn / 64;  // mask words per row = 32

// ---------------------------------------------------------------- normalize
__global__ __launch_bounds__(128) void k_norm(const float* __restrict__ emb,
                                              float* __restrict__ ne) {
    const int r = blockIdx.x, c = threadIdx.x;
    const float v = emb[(size_t)r * HID + c];
    __shared__ float red[128];
    red[c] = v * v;
    __syncthreads();
    for (int s = 64; s > 0; s >>= 1) {
        if (c < s) red[c] += red[c + s];
        __syncthreads();
    }
    const float tot = red[0];
    ne[(size_t)r * HID + c] = v * rsqrtf(tot + 1e-12f);
}

// ---------------- fused: [adj 128x64 tiles, 512 blocks] || [projhid, 512 blocks]
struct AdjS {
    float As[32][132];          // k-major A tile (128 rows)
    float Bs[32][68];           // k-major B tile (64 rows)
    unsigned char mb[128][8];   // packed mask bytes
};

__global__ __launch_bounds__(256) void k_adjproj(
        const float* __restrict__ ne,  u64* __restrict__ maskw,
        const float* __restrict__ x,   const float* __restrict__ Wp,
        const float* __restrict__ bp,  const float* __restrict__ W1,
        const float* __restrict__ a1s, const float* __restrict__ a1d,
        float* __restrict__ hh1, float* __restrict__ s1s, float* __restrict__ s1d) {
    __shared__ __align__(16) unsigned char smem[sizeof(AdjS)];
    const int t = threadIdx.x;

    if (blockIdx.x < 512) {
        // ---------------- adj: 128(i) x 64(j) tile, 4x8 acc/thread, BK=32
        AdjS& S = *reinterpret_cast<AdjS*>(smem);
        const int i0 = (blockIdx.x >> 5) * 128;
        const int j0 = (blockIdx.x & 31) * 64;
        const int tx = t & 7, ty = t >> 3;          // tx: 8 j-groups, ty: 32 i-groups
        const int sra = t >> 1, sha = (t & 1) * 16; // A staging
        const int srb = t >> 2, shb = (t & 3) * 8;  // B staging

        float acc[4][8];
        #pragma unroll
        for (int a = 0; a < 4; ++a)
            #pragma unroll
            for (int b = 0; b < 8; ++b) acc[a][b] = 0.f;

        for (int kc = 0; kc < HID; kc += 32) {
            const float* gA = ne + (size_t)(i0 + sra) * HID + kc + sha;
            const float* gB = ne + (size_t)(j0 + srb) * HID + kc + shb;
            #pragma unroll
            for (int e = 0; e < 16; e += 4) {
                const float4 va = *reinterpret_cast<const float4*>(gA + e);
                S.As[sha + e + 0][sra] = va.x; S.As[sha + e + 1][sra] = va.y;
                S.As[sha + e + 2][sra] = va.z; S.As[sha + e + 3][sra] = va.w;
            }
            #pragma unroll
            for (int e = 0; e < 8; e += 4) {
                const float4 vb = *reinterpret_cast<const float4*>(gB + e);
                S.Bs[shb + e + 0][srb] = vb.x; S.Bs[shb + e + 1][srb] = vb.y;
                S.Bs[shb + e + 2][srb] = vb.z; S.Bs[shb + e + 3][srb] = vb.w;
            }
            __syncthreads();
            #pragma unroll 8
            for (int k = 0; k < 32; ++k) {
                float a[4], b[8];
                *reinterpret_cast<float4*>(a)     = *reinterpret_cast<const float4*>(&S.As[k][ty * 4]);
                *reinterpret_cast<float4*>(&b[0]) = *reinterpret_cast<const float4*>(&S.Bs[k][tx * 8]);
                *reinterpret_cast<float4*>(&b[4]) = *reinterpret_cast<const float4*>(&S.Bs[k][tx * 8 + 4]);
                #pragma unroll
                for (int ii = 0; ii < 4; ++ii)
                    #pragma unroll
                    for (int jj = 0; jj < 8; ++jj)
                        acc[ii][jj] += a[ii] * b[jj];
            }
            __syncthreads();
        }

        #pragma unroll
        for (int e = 0; e < 4; ++e) {
            unsigned byte = 0;
            #pragma unroll
            for (int jj = 0; jj < 8; ++jj)
                if (acc[e][jj] > 0.5f) byte |= (1u << jj);
            S.mb[ty * 4 + e][tx] = (unsigned char)byte;
        }
        __syncthreads();
        if (t < 128) {
            const u64 bits = *reinterpret_cast<const u64*>(S.mb[t]);
            maskw[(size_t)(i0 + t) * NW + (blockIdx.x & 31)] = bits;
        }
    } else {
        // ---------------- projhid: 16 rows/block (two 128-thread halves x 8)
        float (*hl)[128] = reinterpret_cast<float(*)[128]>(smem);
        const int h  = t >> 7;          // half 0/1
        const int c  = t & 127;         // channel
        const int r0 = (blockIdx.x - 512) * 16 + h * 8;

        float acc[8];
        const float bias = bp[c];
        #pragma unroll
        for (int r = 0; r < 8; ++r) acc[r] = bias;
        #pragma unroll 4
        for (int k = 0; k < INDIM; ++k) {
            const float wp = Wp[k * HID + c];
            #pragma unroll
            for (int r = 0; r < 8; ++r)
                acc[r] += x[(size_t)(r0 + r) * INDIM + k] * wp;  // block-uniform -> s_load
        }
        #pragma unroll
        for (int r = 0; r < 8; ++r) hl[h * 8 + r][c] = acc[r];
        __syncthreads();

        float a2[8];
        #pragma unroll
        for (int r = 0; r < 8; ++r) a2[r] = 0.f;
        #pragma unroll 4
        for (int k = 0; k < HID; ++k) {
            const float w = W1[k * HID + c];
            #pragma unroll
            for (int r = 0; r < 8; ++r)
                a2[r] += hl[h * 8 + r][k] * w;                   // LDS broadcast
        }
        const float as = a1s[c], ad = a1d[c];
        #pragma unroll
        for (int r = 0; r < 8; ++r) {
            hh1[(size_t)(r0 + r) * HID + c] = a2[r];
            float vs = a2[r] * as;
            float vd = a2[r] * ad;
            #pragma unroll
            for (int m = 1; m < 32; m <<= 1) {
                vs += __shfl_xor(vs, m, 32);
                vd += __shfl_xor(vd, m, 32);
            }
            if ((c & 31) == 0) {
                s1s[(size_t)(r0 + r) * 4 + (c >> 5)] = vs;
                s1d[(size_t)(r0 + r) * 4 + (c >> 5)] = vd;
            }
        }
    }
}

// --------- hh = hin@W ; per-head s_src/s_dst : 8 rows/block (round-9 proven)
__global__ __launch_bounds__(128) void k_hid(const float* __restrict__ hin,
                                             const float* __restrict__ W,
                                             const float* __restrict__ asrc,
                                             const float* __restrict__ adst,
                                             float* __restrict__ hh,
                                             float* __restrict__ ssrc,
                                             float* __restrict__ sdst) {
    const int r0 = blockIdx.x * 8;
    const int c  = threadIdx.x;
    float acc[8];
    #pragma unroll
    for (int r = 0; r < 8; ++r) acc[r] = 0.f;
    #pragma unroll 4
    for (int k = 0; k < HID; ++k) {
        const float w = W[k * HID + c];
        #pragma unroll
        for (int r = 0; r < 8; ++r)
            acc[r] += hin[(size_t)(r0 + r) * HID + k] * w;    // block-uniform -> s_load
    }
    const float as = asrc[c], ad = adst[c];
    #pragma unroll
    for (int r = 0; r < 8; ++r) {
        hh[(size_t)(r0 + r) * HID + c] = acc[r];
        float vs = acc[r] * as;
        float vd = acc[r] * ad;
        #pragma unroll
        for (int m = 1; m < 32; m <<= 1) {
            vs += __shfl_xor(vs, m, 32);
            vd += __shfl_xor(vd, m, 32);
        }
        if ((c & 31) == 0) {
            ssrc[(size_t)(r0 + r) * 4 + (c >> 5)] = vs;
            sdst[(size_t)(r0 + r) * 4 + (c >> 5)] = vd;
        }
    }
}

// ------------- masked online-softmax aggregation, batched (bitmask scan)
// GELU=1: apply exact-erf GELU to the output. Writes f32.
template <int GELU>
__global__ __launch_bounds__(64) void k_gat(const float* __restrict__ hh,
                                            const float* __restrict__ ssrc,
                                            const float* __restrict__ sdst,
                                            const u64* __restrict__ maskw,
                                            const float* __restrict__ bias,
                                            float* __restrict__ out) {
    const int row  = blockIdx.x;        // b*N + i
    const int i    = row & (Nn - 1);
    const int b    = row >> 11;
    const int lane = threadIdx.x;       // channels: lane (heads 0/1), lane+64 (heads 2/3)
    const int h0   = lane >> 5;
    const int h1   = 2 + h0;
    const float sd0 = sdst[(size_t)row * 4 + h0];
    const float sd1 = sdst[(size_t)row * 4 + h1];
    const u64* mrow = maskw + (size_t)i * NW;

    float m0 = -INFINITY, l0 = 0.f, a0 = 0.f;
    float m1 = -INFINITY, l1 = 0.f, a1 = 0.f;

    for (int w = 0; w < NW; ++w) {
        u64 word = mrow[w];
        while (word) {
            const int bit = __builtin_ctzll(word);
            word &= word - 1;
            const int jr = (b << 11) + (w << 6) + bit;
            float e0 = sd0 + ssrc[(size_t)jr * 4 + h0];
            e0 = e0 > 0.f ? e0 : 0.2f * e0;
            float e1 = sd1 + ssrc[(size_t)jr * 4 + h1];
            e1 = e1 > 0.f ? e1 : 0.2f * e1;
            const float v0 = hh[(size_t)jr * HID + lane];
            const float v1 = hh[(size_t)jr * HID + 64 + lane];
            float nm = fmaxf(m0, e0);
            float sc = __expf(m0 - nm);
            float p  = __expf(e0 - nm);
            l0 = l0 * sc + p; a0 = a0 * sc + p * v0; m0 = nm;
            nm = fmaxf(m1, e1);
            sc = __expf(m1 - nm);
            p  = __expf(e1 - nm);
            l1 = l1 * sc + p; a1 = a1 * sc + p * v1; m1 = nm;
        }
    }

    float o0 = (l0 > 0.f ? a0 / l0 : 0.f) + bias[lane];
    float o1 = (l1 > 0.f ? a1 / l1 : 0.f) + bias[64 + lane];
    if constexpr (GELU) {
        o0 = 0.5f * o0 * (1.f + erff(o0 * 0.70710678118654752f));
        o1 = 0.5f * o1 * (1.f + erff(o1 * 0.70710678118654752f));
    }
    out[(size_t)row * HID + lane]      = o0;
    out[(size_t)row * HID + 64 + lane] = o1;
}

// ---------------------------------------------------------------- launcher
extern "C" void kernel_launch(void* const* d_in, const int* in_sizes, int n_in,
                              void* d_out, int out_size, void* d_ws, size_t ws_size,
                              hipStream_t stream) {
    // dict order: x, embedding, Wp, bp, W1, a1_src, a1_dst, b1, W2, a2_src, a2_dst, b2
    const float* x   = (const float*)d_in[0];
    const float* emb = (const float*)d_in[1];
    const float* Wp  = (const float*)d_in[2];
    const float* bp  = (const float*)d_in[3];
    const float* W1  = (const float*)d_in[4];
    const float* a1s = (const float*)d_in[5];
    const float* a1d = (const float*)d_in[6];
    const float* b1  = (const float*)d_in[7];
    const float* W2  = (const float*)d_in[8];
    const float* a2s = (const float*)d_in[9];
    const float* a2d = (const float*)d_in[10];
    const float* b2  = (const float*)d_in[11];

    // Workspace: ~14 MB
    char* ws = (char*)d_ws;
    float* ne   = (float*)ws; ws += (size_t)Nn * HID * 4;          // 1 MB
    u64*  maskw = (u64*)ws;   ws += (size_t)Nn * NW * 8;           // 512 KB
    float* hh1  = (float*)ws; ws += (size_t)Bb * Nn * HID * 4;     // 4 MB
    float* g    = (float*)ws; ws += (size_t)Bb * Nn * HID * 4;     // 4 MB
    float* hh2  = (float*)ws; ws += (size_t)Bb * Nn * HID * 4;     // 4 MB
    float* s1s  = (float*)ws; ws += (size_t)Bb * Nn * 4 * 4;       // 128 KB
    float* s1d  = (float*)ws; ws += (size_t)Bb * Nn * 4 * 4;       // 128 KB
    float* s2s  = (float*)ws; ws += (size_t)Bb * Nn * 4 * 4;       // 128 KB
    float* s2d  = (float*)ws; ws += (size_t)Bb * Nn * 4 * 4;       // 128 KB

    k_norm<<<Nn, 128, 0, stream>>>(emb, ne);
    k_adjproj<<<1024, 256, 0, stream>>>(ne, maskw, x, Wp, bp, W1, a1s, a1d,
                                        hh1, s1s, s1d);
    k_gat<1><<<Bb * Nn, 64, 0, stream>>>(hh1, s1s, s1d, maskw, b1, g);
    k_hid<<<Bb * Nn / 8, 128, 0, stream>>>(g, W2, a2s, a2d, hh2, s2s, s2d);
    k_gat<0><<<Bb * Nn, 64, 0, stream>>>(hh2, s2s, s2d, maskw, b2, (float*)d_out);
}

// Round 12
// 56.199 us; speedup vs baseline: 1.5067x; 1.1660x over previous
//
#include <hip/hip_runtime.h>
#include <hip/hip_bf16.h>

using u64 = unsigned long long;

constexpr int Bb    = 4;
constexpr int Nn    = 2048;
constexpr int INDIM = 64;
constexpr int HID   = 128;      // HIDDEN == OUT_DIM == 128
constexpr int NW    = Nn / 64;  // mask words per row = 32

// ------------------------------- per-row rsqrt(sum e^2 + eps), wave per row
__global__ __launch_bounds__(256) void k_rs(const float* __restrict__ emb,
                                            float* __restrict__ rs) {
    const int row  = blockIdx.x * 4 + (threadIdx.x >> 6);
    const int lane = threadIdx.x & 63;
    const float v0 = emb[(size_t)row * HID + lane];
    const float v1 = emb[(size_t)row * HID + 64 + lane];
    float s = v0 * v0 + v1 * v1;
    #pragma unroll
    for (int m = 1; m < 64; m <<= 1) s += __shfl_xor(s, m, 64);
    if (lane == 0) rs[row] = rsqrtf(s + 1e-12f);
}

// ---------------- fused: [adj 128x64 tiles, 512 blocks] || [projhid, 512 blocks]
struct AdjS {
    float As[32][132];          // k-major A tile (128 rows)
    float Bs[32][68];           // k-major B tile (64 rows)
    unsigned char mb[128][8];   // packed mask bytes
};

__global__ __launch_bounds__(256) void k_adjproj(
        const float* __restrict__ emb, const float* __restrict__ rs,
        u64* __restrict__ maskw,
        const float* __restrict__ x,   const float* __restrict__ Wp,
        const float* __restrict__ bp,  const float* __restrict__ W1,
        const float* __restrict__ a1s, const float* __restrict__ a1d,
        float* __restrict__ hh1, float* __restrict__ s1s, float* __restrict__ s1d) {
    __shared__ __align__(16) unsigned char smem[sizeof(AdjS)];
    const int t = threadIdx.x;

    if (blockIdx.x < 512) {
        // ---------------- adj: 128(i) x 64(j) tile, 4x8 acc/thread, BK=32
        AdjS& S = *reinterpret_cast<AdjS*>(smem);
        const int i0 = (blockIdx.x >> 5) * 128;
        const int j0 = (blockIdx.x & 31) * 64;
        const int tx = t & 7, ty = t >> 3;          // tx: 8 j-groups, ty: 32 i-groups
        const int sra = t >> 1, sha = (t & 1) * 16; // A staging
        const int srb = t >> 2, shb = (t & 3) * 8;  // B staging

        float acc[4][8];
        #pragma unroll
        for (int a = 0; a < 4; ++a)
            #pragma unroll
            for (int b = 0; b < 8; ++b) acc[a][b] = 0.f;

        for (int kc = 0; kc < HID; kc += 32) {
            const float* gA = emb + (size_t)(i0 + sra) * HID + kc + sha;
            const float* gB = emb + (size_t)(j0 + srb) * HID + kc + shb;
            #pragma unroll
            for (int e = 0; e < 16; e += 4) {
                const float4 va = *reinterpret_cast<const float4*>(gA + e);
                S.As[sha + e + 0][sra] = va.x; S.As[sha + e + 1][sra] = va.y;
                S.As[sha + e + 2][sra] = va.z; S.As[sha + e + 3][sra] = va.w;
            }
            #pragma unroll
            for (int e = 0; e < 8; e += 4) {
                const float4 vb = *reinterpret_cast<const float4*>(gB + e);
                S.Bs[shb + e + 0][srb] = vb.x; S.Bs[shb + e + 1][srb] = vb.y;
                S.Bs[shb + e + 2][srb] = vb.z; S.Bs[shb + e + 3][srb] = vb.w;
            }
            __syncthreads();
            #pragma unroll 8
            for (int k = 0; k < 32; ++k) {
                float a[4], b[8];
                *reinterpret_cast<float4*>(a)     = *reinterpret_cast<const float4*>(&S.As[k][ty * 4]);
                *reinterpret_cast<float4*>(&b[0]) = *reinterpret_cast<const float4*>(&S.Bs[k][tx * 8]);
                *reinterpret_cast<float4*>(&b[4]) = *reinterpret_cast<const float4*>(&S.Bs[k][tx * 8 + 4]);
                #pragma unroll
                for (int ii = 0; ii < 4; ++ii)
                    #pragma unroll
                    for (int jj = 0; jj < 8; ++jj)
                        acc[ii][jj] += a[ii] * b[jj];
            }
            __syncthreads();
        }

        float rsj[8];
        #pragma unroll
        for (int jj = 0; jj < 8; ++jj) rsj[jj] = rs[j0 + tx * 8 + jj];
        #pragma unroll
        for (int e = 0; e < 4; ++e) {
            const float rsi = rs[i0 + ty * 4 + e];
            unsigned byte = 0;
            #pragma unroll
            for (int jj = 0; jj < 8; ++jj)
                if (acc[e][jj] * rsi * rsj[jj] > 0.5f) byte |= (1u << jj);
            S.mb[ty * 4 + e][tx] = (unsigned char)byte;
        }
        __syncthreads();
        if (t < 128) {
            const u64 bits = *reinterpret_cast<const u64*>(S.mb[t]);
            maskw[(size_t)(i0 + t) * NW + (blockIdx.x & 31)] = bits;
        }
    } else {
        // ---------------- projhid: 16 rows/block (two 128-thread halves x 8)
        float (*hl)[128] = reinterpret_cast<float(*)[128]>(smem);
        const int h  = t >> 7;          // half 0/1
        const int c  = t & 127;         // channel
        const int r0 = (blockIdx.x - 512) * 16 + h * 8;

        float acc[8];
        const float bias = bp[c];
        #pragma unroll
        for (int r = 0; r < 8; ++r) acc[r] = bias;
        #pragma unroll 4
        for (int k = 0; k < INDIM; ++k) {
            const float wp = Wp[k * HID + c];
            #pragma unroll
            for (int r = 0; r < 8; ++r)
                acc[r] += x[(size_t)(r0 + r) * INDIM + k] * wp;  // block-uniform -> s_load
        }
        #pragma unroll
        for (int r = 0; r < 8; ++r) hl[h * 8 + r][c] = acc[r];
        __syncthreads();

        float a2[8];
        #pragma unroll
        for (int r = 0; r < 8; ++r) a2[r] = 0.f;
        #pragma unroll 4
        for (int k = 0; k < HID; ++k) {
            const float w = W1[k * HID + c];
            #pragma unroll
            for (int r = 0; r < 8; ++r)
                a2[r] += hl[h * 8 + r][k] * w;                   // LDS broadcast
        }
        const float as = a1s[c], ad = a1d[c];
        #pragma unroll
        for (int r = 0; r < 8; ++r) {
            hh1[(size_t)(r0 + r) * HID + c] = a2[r];
            float vs = a2[r] * as;
            float vd = a2[r] * ad;
            #pragma unroll
            for (int m = 1; m < 32; m <<= 1) {
                vs += __shfl_xor(vs, m, 32);
                vd += __shfl_xor(vd, m, 32);
            }
            if ((c & 31) == 0) {
                s1s[(size_t)(r0 + r) * 4 + (c >> 5)] = vs;
                s1d[(size_t)(r0 + r) * 4 + (c >> 5)] = vd;
            }
        }
    }
}

// ------- fused: gat layer1 (+GELU) with fast word-scan ; hh2 = g@W2 ; s2.
// 8 rows/block, 128 threads (2 waves); wave w scans rows 4w..4w+3.
__global__ __launch_bounds__(128) void k_gathid2(
        const float* __restrict__ hh1,
        const float* __restrict__ s1s, const float* __restrict__ s1d,
        const u64* __restrict__ maskw, const float* __restrict__ b1v,
        const float* __restrict__ W2,
        const float* __restrict__ a2s, const float* __restrict__ a2d,
        float* __restrict__ hh2,
        float* __restrict__ s2s, float* __restrict__ s2d) {
    const int r0   = blockIdx.x * 8;
    const int bb   = r0 >> 11;          // batch index
    const int t    = threadIdx.x;
    const int wv   = t >> 6;            // wave 0/1
    const int lane = t & 63;
    const int h0   = lane >> 5, h1 = 2 + h0;
    __shared__ float gl[8][128];

    for (int rr = 0; rr < 4; ++rr) {
        const int r   = wv * 4 + rr;
        const int row = r0 + r, i = row & (Nn - 1);
        const u64* mrow = maskw + (size_t)i * NW;
        const u64 myw = (lane < NW) ? mrow[lane] : 0ULL;   // one coalesced round
        u64 nz = __ballot(myw != 0ULL);
        const float sd0 = s1d[(size_t)row * 4 + h0];
        const float sd1 = s1d[(size_t)row * 4 + h1];
        float m0 = -INFINITY, l0 = 0.f, a0 = 0.f;
        float m1 = -INFINITY, l1 = 0.f, a1 = 0.f;
        while (nz) {
            const int w = __builtin_ctzll(nz); nz &= nz - 1;
            u64 word = __shfl(myw, w, 64);
            while (word) {
                const int bit = __builtin_ctzll(word); word &= word - 1;
                const int jr = (bb << 11) + (w << 6) + bit;
                float e0 = sd0 + s1s[(size_t)jr * 4 + h0];
                e0 = e0 > 0.f ? e0 : 0.2f * e0;
                float e1 = sd1 + s1s[(size_t)jr * 4 + h1];
                e1 = e1 > 0.f ? e1 : 0.2f * e1;
                const float v0 = hh1[(size_t)jr * HID + lane];
                const float v1 = hh1[(size_t)jr * HID + 64 + lane];
                float nm = fmaxf(m0, e0);
                float sc = __expf(m0 - nm);
                float p  = __expf(e0 - nm);
                l0 = l0 * sc + p; a0 = a0 * sc + p * v0; m0 = nm;
                nm = fmaxf(m1, e1);
                sc = __expf(m1 - nm);
                p  = __expf(e1 - nm);
                l1 = l1 * sc + p; a1 = a1 * sc + p * v1; m1 = nm;
            }
        }
        float o0 = (l0 > 0.f ? a0 / l0 : 0.f) + b1v[lane];
        float o1 = (l1 > 0.f ? a1 / l1 : 0.f) + b1v[64 + lane];
        o0 = 0.5f * o0 * (1.f + erff(o0 * 0.70710678118654752f));
        o1 = 0.5f * o1 * (1.f + erff(o1 * 0.70710678118654752f));
        gl[r][lane]      = o0;
        gl[r][64 + lane] = o1;
    }
    __syncthreads();

    // GEMV: hh2 = g@W2 ; per-head s2 reductions. c = t (128 channels).
    const int c = t;
    float acc[8];
    #pragma unroll
    for (int r = 0; r < 8; ++r) acc[r] = 0.f;
    #pragma unroll 4
    for (int k = 0; k < HID; ++k) {
        const float w = W2[k * HID + c];
        #pragma unroll
        for (int r = 0; r < 8; ++r)
            acc[r] += gl[r][k] * w;                           // LDS broadcast
    }
    const float as = a2s[c], ad = a2d[c];
    #pragma unroll
    for (int r = 0; r < 8; ++r) {
        hh2[(size_t)(r0 + r) * HID + c] = acc[r];
        float vs = acc[r] * as;
        float vd = acc[r] * ad;
        #pragma unroll
        for (int m = 1; m < 32; m <<= 1) {
            vs += __shfl_xor(vs, m, 32);
            vd += __shfl_xor(vd, m, 32);
        }
        if ((c & 31) == 0) {
            s2s[(size_t)(r0 + r) * 4 + (c >> 5)] = vs;
            s2d[(size_t)(r0 + r) * 4 + (c >> 5)] = vd;
        }
    }
}

// ------------- final masked aggregation (fast word-scan), writes f32 d_out
__global__ __launch_bounds__(64) void k_gat(const float* __restrict__ hh,
                                            const float* __restrict__ ssrc,
                                            const float* __restrict__ sdst,
                                            const u64* __restrict__ maskw,
                                            const float* __restrict__ bias,
                                            float* __restrict__ out) {
    const int row  = blockIdx.x;        // b*N + i
    const int i    = row & (Nn - 1);
    const int b    = row >> 11;
    const int lane = threadIdx.x;       // channels: lane (heads 0/1), lane+64 (heads 2/3)
    const int h0   = lane >> 5;
    const int h1   = 2 + h0;
    const float sd0 = sdst[(size_t)row * 4 + h0];
    const float sd1 = sdst[(size_t)row * 4 + h1];
    const u64* mrow = maskw + (size_t)i * NW;

    const u64 myw = (lane < NW) ? mrow[lane] : 0ULL;      // one coalesced round
    u64 nz = __ballot(myw != 0ULL);

    float m0 = -INFINITY, l0 = 0.f, a0 = 0.f;
    float m1 = -INFINITY, l1 = 0.f, a1 = 0.f;

    while (nz) {
        const int w = __builtin_ctzll(nz); nz &= nz - 1;
        u64 word = __shfl(myw, w, 64);
        while (word) {
            const int bit = __builtin_ctzll(word); word &= word - 1;
            const int jr = (b << 11) + (w << 6) + bit;
            float e0 = sd0 + ssrc[(size_t)jr * 4 + h0];
            e0 = e0 > 0.f ? e0 : 0.2f * e0;
            float e1 = sd1 + ssrc[(size_t)jr * 4 + h1];
            e1 = e1 > 0.f ? e1 : 0.2f * e1;
            const float v0 = hh[(size_t)jr * HID + lane];
            const float v1 = hh[(size_t)jr * HID + 64 + lane];
            float nm = fmaxf(m0, e0);
            float sc = __expf(m0 - nm);
            float p  = __expf(e0 - nm);
            l0 = l0 * sc + p; a0 = a0 * sc + p * v0; m0 = nm;
            nm = fmaxf(m1, e1);
            sc = __expf(m1 - nm);
            p  = __expf(e1 - nm);
            l1 = l1 * sc + p; a1 = a1 * sc + p * v1; m1 = nm;
        }
    }

    out[(size_t)row * HID + lane]      = (l0 > 0.f ? a0 / l0 : 0.f) + bias[lane];
    out[(size_t)row * HID + 64 + lane] = (l1 > 0.f ? a1 / l1 : 0.f) + bias[64 + lane];
}

// ---------------------------------------------------------------- launcher
extern "C" void kernel_launch(void* const* d_in, const int* in_sizes, int n_in,
                              void* d_out, int out_size, void* d_ws, size_t ws_size,
                              hipStream_t stream) {
    // dict order: x, embedding, Wp, bp, W1, a1_src, a1_dst, b1, W2, a2_src, a2_dst, b2
    const float* x   = (const float*)d_in[0];
    const float* emb = (const float*)d_in[1];
    const float* Wp  = (const float*)d_in[2];
    const float* bp  = (const float*)d_in[3];
    const float* W1  = (const float*)d_in[4];
    const float* a1s = (const float*)d_in[5];
    const float* a1d = (const float*)d_in[6];
    const float* b1  = (const float*)d_in[7];
    const float* W2  = (const float*)d_in[8];
    const float* a2s = (const float*)d_in[9];
    const float* a2d = (const float*)d_in[10];
    const float* b2  = (const float*)d_in[11];

    // Workspace: ~9 MB
    char* ws = (char*)d_ws;
    float* rs   = (float*)ws; ws += (size_t)Nn * 4;                // 8 KB
    u64*  maskw = (u64*)ws;   ws += (size_t)Nn * NW * 8;           // 512 KB
    float* hh1  = (float*)ws; ws += (size_t)Bb * Nn * HID * 4;     // 4 MB
    float* hh2  = (float*)ws; ws += (size_t)Bb * Nn * HID * 4;     // 4 MB
    float* s1s  = (float*)ws; ws += (size_t)Bb * Nn * 4 * 4;       // 128 KB
    float* s1d  = (float*)ws; ws += (size_t)Bb * Nn * 4 * 4;       // 128 KB
    float* s2s  = (float*)ws; ws += (size_t)Bb * Nn * 4 * 4;       // 128 KB
    float* s2d  = (float*)ws; ws += (size_t)Bb * Nn * 4 * 4;       // 128 KB

    k_rs<<<Nn / 4, 256, 0, stream>>>(emb, rs);
    k_adjproj<<<1024, 256, 0, stream>>>(emb, rs, maskw, x, Wp, bp, W1, a1s, a1d,
                                        hh1, s1s, s1d);
    k_gathid2<<<Bb * Nn / 8, 128, 0, stream>>>(hh1, s1s, s1d, maskw, b1,
                                               W2, a2s, a2d, hh2, s2s, s2d);
    k_gat<<<Bb * Nn, 64, 0, stream>>>(hh2, s2s, s2d, maskw, b2, (float*)d_out);
}